// Round 8
// baseline (62718.469 us; speedup 1.0000x reference)
//
#include <hip/hip_runtime.h>
#include <math.h>

#define NB 8
#define NS 2048
#define NE 768
#define NU 1024
#define NBB 512
#define NH 3072
#define NBS (NB*NS)   // 16384
#define NWG 128

typedef float f32x4v __attribute__((ext_vector_type(4)));
typedef __bf16 bf16x8v __attribute__((ext_vector_type(8)));
typedef unsigned short u16x8v __attribute__((ext_vector_type(8)));
typedef unsigned short u16x4v __attribute__((ext_vector_type(4)));

__device__ __forceinline__ unsigned short f2bf(float f) {
  unsigned int u = __builtin_bit_cast(unsigned int, f);
  u = (u + 0x7fffu + ((u >> 16) & 1u)) >> 16;
  return (unsigned short)u;
}
__device__ __forceinline__ float bf2f(unsigned short h) {
  unsigned int u = ((unsigned int)h) << 16;
  return __builtin_bit_cast(float, u);
}

// agent-scope (device) relaxed ops: sc0 sc1 loads/stores, coherent at LLC,
// no cache writeback/invalidate instructions.
__device__ __forceinline__ float ald(const float* p) {
  return __hip_atomic_load((const float*)p, __ATOMIC_RELAXED, __HIP_MEMORY_SCOPE_AGENT);
}
__device__ __forceinline__ void ast(float* p, float v) {
  __hip_atomic_store(p, v, __ATOMIC_RELAXED, __HIP_MEMORY_SCOPE_AGENT);
}
__device__ __forceinline__ uint2 ald2u(const float* p) {
  unsigned long long v = __hip_atomic_load((const unsigned long long*)p,
                             __ATOMIC_RELAXED, __HIP_MEMORY_SCOPE_AGENT);
  return __builtin_bit_cast(uint2, v);
}
// store a PAIR of floats with 8-bit generation tag in each low mantissa byte
__device__ __forceinline__ void ast2_tag(float* p, float a, float b, unsigned tag) {
  unsigned ua = (__builtin_bit_cast(unsigned, a) & 0xFFFFFF00u) | tag;
  unsigned ub = (__builtin_bit_cast(unsigned, b) & 0xFFFFFF00u) | tag;
  unsigned long long v = ((unsigned long long)ub << 32) | ua;
  __hip_atomic_store((unsigned long long*)p, v, __ATOMIC_RELAXED, __HIP_MEMORY_SCOPE_AGENT);
}

// ---------------- transpose kernels (weight prep) ----------------
__global__ __launch_bounds__(256) void tr_f32(const float* __restrict__ in,
                                              float* __restrict__ out, int R, int C) {
  __shared__ float tile[32][33];
  int c0 = blockIdx.x * 32, r0 = blockIdx.y * 32;
  int tx = threadIdx.x, ty = threadIdx.y;  // block (32,8)
  #pragma unroll
  for (int i = 0; i < 32; i += 8)
    tile[ty + i][tx] = in[(long)(r0 + ty + i) * C + c0 + tx];
  __syncthreads();
  #pragma unroll
  for (int i = 0; i < 32; i += 8)
    out[(long)(c0 + ty + i) * R + r0 + tx] = tile[tx][ty + i];
}

__global__ __launch_bounds__(256) void tr_f32_bf16(const float* __restrict__ in,
                                                   unsigned short* __restrict__ out, int R, int C) {
  __shared__ float tile[32][33];
  int c0 = blockIdx.x * 32, r0 = blockIdx.y * 32;
  int tx = threadIdx.x, ty = threadIdx.y;
  #pragma unroll
  for (int i = 0; i < 32; i += 8)
    tile[ty + i][tx] = in[(long)(r0 + ty + i) * C + c0 + tx];
  __syncthreads();
  #pragma unroll
  for (int i = 0; i < 32; i += 8)
    out[(long)(c0 + ty + i) * R + r0 + tx] = f2bf(tile[tx][ty + i]);
}

// transpose + split into bf16 hi/lo pair (for ~fp32-precision GEMM)
__global__ __launch_bounds__(256) void tr_f32_bf16split(const float* __restrict__ in,
    unsigned short* __restrict__ oh, unsigned short* __restrict__ ol, int R, int C) {
  __shared__ float tile[32][33];
  int c0 = blockIdx.x * 32, r0 = blockIdx.y * 32;
  int tx = threadIdx.x, ty = threadIdx.y;
  #pragma unroll
  for (int i = 0; i < 32; i += 8)
    tile[ty + i][tx] = in[(long)(r0 + ty + i) * C + c0 + tx];
  __syncthreads();
  #pragma unroll
  for (int i = 0; i < 32; i += 8) {
    float v = tile[tx][ty + i];
    unsigned short h = f2bf(v);
    long idx = (long)(c0 + ty + i) * R + r0 + tx;
    oh[idx] = h;
    ol[idx] = f2bf(v - bf2f(h));
  }
}

// ---------------- LayerNorm (one wave per row of 768) -> bf16 hi/lo out ----------------
__global__ __launch_bounds__(256) void ln_kernel(const float* __restrict__ in,
    const float* __restrict__ gw, const float* __restrict__ bw,
    unsigned short* __restrict__ outh, unsigned short* __restrict__ outl) {
  int lane = threadIdx.x & 63;
  long row = (long)blockIdx.x * 4 + (threadIdx.x >> 6);
  const float4* rp = (const float4*)(in + row * NE);
  float4 v[3];
  float s = 0.f, sq = 0.f;
  #pragma unroll
  for (int j = 0; j < 3; ++j) {
    v[j] = rp[lane + j * 64];
    s += v[j].x + v[j].y + v[j].z + v[j].w;
    sq += v[j].x*v[j].x + v[j].y*v[j].y + v[j].z*v[j].z + v[j].w*v[j].w;
  }
  #pragma unroll
  for (int m = 1; m < 64; m <<= 1) { s += __shfl_xor(s, m); sq += __shfl_xor(sq, m); }
  float mu = s * (1.f / NE);
  float rs = rsqrtf(sq * (1.f / NE) - mu * mu + 1e-5f);
  #pragma unroll
  for (int j = 0; j < 3; ++j) {
    int c4 = lane + j * 64;
    float4 g4 = ((const float4*)gw)[c4];
    float4 b4 = ((const float4*)bw)[c4];
    float f0 = (v[j].x - mu) * rs * g4.x + b4.x;
    float f1 = (v[j].y - mu) * rs * g4.y + b4.y;
    float f2 = (v[j].z - mu) * rs * g4.z + b4.z;
    float f3 = (v[j].w - mu) * rs * g4.w + b4.w;
    u16x4v oh, ol;
    oh[0] = f2bf(f0); ol[0] = f2bf(f0 - bf2f(oh[0]));
    oh[1] = f2bf(f1); ol[1] = f2bf(f1 - bf2f(oh[1]));
    oh[2] = f2bf(f2); ol[2] = f2bf(f2 - bf2f(oh[2]));
    oh[3] = f2bf(f3); ol[3] = f2bf(f3 - bf2f(oh[3]));
    *(u16x4v*)(outh + row * NE + (long)c4 * 4) = oh;
    *(u16x4v*)(outl + row * NE + (long)c4 * 4) = ol;
  }
}

// ---------------- bf16 MFMA GEMM: C[M,N] = A[M,K] @ Bt[N,K]^T (+bias, epilogue) ---
// EPI 0: Cf = acc + bias            (fp32 out)
// EPI 1: Cb = bf16(gelu(acc+bias))  (bf16 out)
// EPI 2: Cf = acc + bias + res      (fp32 out, residual add; res may alias Cf)
// EPI 3: Cf += acc                  (fp32 accumulate, no bias)
template<int EPI>
__global__ __launch_bounds__(256) void gemm_bf16(
    const unsigned short* __restrict__ A, const unsigned short* __restrict__ Bt,
    const float* __restrict__ bias, const float* res,
    float* Cf, unsigned short* Cb, int M, int N, int K)
{
  __shared__ unsigned short lA[128][72];
  __shared__ unsigned short lB[128][72];
  int tid = threadIdx.x;
  int lane = tid & 63, wave = tid >> 6;
  int wr = wave >> 1, wc = wave & 1;
  int r15 = lane & 15, hi = lane >> 4;
  int ntn = N >> 7;
  long m0 = (long)(blockIdx.x / ntn) << 7;
  long n0 = (long)(blockIdx.x % ntn) << 7;
  f32x4v acc[4][4];
  #pragma unroll
  for (int m = 0; m < 4; ++m)
    #pragma unroll
    for (int n = 0; n < 4; ++n) acc[m][n] = (f32x4v){0.f, 0.f, 0.f, 0.f};

  for (int kt = 0; kt < K; kt += 64) {
    u16x8v ra[4], rb[4];
    #pragma unroll
    for (int i = 0; i < 4; ++i) {
      int c = tid + (i << 8);
      int rw = c >> 3, ko = (c & 7) << 3;
      ra[i] = *(const u16x8v*)(A + (m0 + rw) * K + kt + ko);
      rb[i] = *(const u16x8v*)(Bt + (n0 + rw) * K + kt + ko);
    }
    __syncthreads();
    #pragma unroll
    for (int i = 0; i < 4; ++i) {
      int c = tid + (i << 8);
      int rw = c >> 3, ko = (c & 7) << 3;
      *(u16x8v*)(&lA[rw][ko]) = ra[i];
      *(u16x8v*)(&lB[rw][ko]) = rb[i];
    }
    __syncthreads();
    #pragma unroll
    for (int ks = 0; ks < 64; ks += 32) {
      bf16x8v af[4], bfr[4];
      #pragma unroll
      for (int m = 0; m < 4; ++m)
        af[m] = *(const bf16x8v*)(&lA[wr * 64 + m * 16 + r15][ks + hi * 8]);
      #pragma unroll
      for (int n = 0; n < 4; ++n)
        bfr[n] = *(const bf16x8v*)(&lB[wc * 64 + n * 16 + r15][ks + hi * 8]);
      #pragma unroll
      for (int m = 0; m < 4; ++m)
        #pragma unroll
        for (int n = 0; n < 4; ++n)
          acc[m][n] = __builtin_amdgcn_mfma_f32_16x16x32_bf16(af[m], bfr[n], acc[m][n], 0, 0, 0);
    }
  }
  #pragma unroll
  for (int m = 0; m < 4; ++m) {
    long rbase = m0 + wr * 64 + m * 16 + hi * 4;
    #pragma unroll
    for (int n = 0; n < 4; ++n) {
      long cg = n0 + wc * 64 + n * 16 + r15;
      float bs = (EPI == 3) ? 0.f : bias[cg];
      #pragma unroll
      for (int e = 0; e < 4; ++e) {
        long row = rbase + e;
        float vv = acc[m][n][e] + bs;
        if (EPI == 0) {
          Cf[row * N + cg] = vv;
        } else if (EPI == 1) {
          float gl = 0.5f * vv * (1.f + erff(vv * 0.70710678118f));
          Cb[row * N + cg] = f2bf(gl);
        } else if (EPI == 2) {
          Cf[row * N + cg] = vv + res[row * N + cg];
        } else {
          Cf[row * N + cg] += vv;
        }
      }
    }
  }
}

// ---------------- persistent scan kernel: PUSH MAILBOXES, zero barriers -------
// 128 WGs x 256 thr. Each block owns a private mailbox that is an exact image
// of its LDS staging buffer: mbH[c] = [b][1024] h floats (32KB), mbB[c] =
// [b][512] bb floats (16KB). Producers PUSH their outputs (tagged with the
// 8-bit generation t%255 in the low mantissa byte) into all 128 consumer
// mailboxes; consumers poll ONLY their own lines (zero line sharing anywhere)
// and the successful poll already holds the data in registers. No grid
// barriers, no flags, no fences; stores are fire-and-forget (per-word tags
// self-validate arrival). WAR-safe: a block can push gen t+1 only after its
// gen-t poll completed, which transitively requires every block to have
// consumed gen t.
__global__ __launch_bounds__(256) void scan_kernel(
    const float* __restrict__ pre, const float* __restrict__ WhhT,
    const float* __restrict__ WhT,
    const float* __restrict__ bf1, const float* __restrict__ bf2,
    const float* __restrict__ bta, const float* __restrict__ btb,
    const float* __restrict__ hx,
    float* mbH, float* mbB, float* __restrict__ cfc, float* hbuf)
{
  __shared__ float lsd[NB * NU];            // 32KB: h image; bb image uses first 16KB
  __shared__ float lpart[4][4][2][8];
  __shared__ float hstage[64];              // [b][vl] this block's h outputs
  __shared__ float bbstage[32];             // [b][jw] this block's bb outputs
  int tid = threadIdx.x;
  int lane = tid & 63, wave = tid >> 6;
  int bx = blockIdx.x;
  int j1 = (bx << 2) + wave;
  int head = lane >> 4, v2 = (lane >> 3) & 1, jsub = lane & 7;
  int vg = (bx << 3) + (wave << 1) + v2;
  const float4* W14 = (const float4*)(WhhT + (long)j1 * NU);
  const float4* W24 = (const float4*)(WhT + ((long)head * NU + vg) * NBB);
  const float4* ls4 = (const float4*)lsd;
  uint2* lsu2 = (uint2*)lsd;

  // weight hoists (r5-proven)
  float4 wreg[4];
  #pragma unroll
  for (int c = 0; c < 4; ++c) wreg[c] = W14[(c << 6) + lane];
  float4 w2reg[16];
  #pragma unroll
  for (int c = 0; c < 16; ++c) w2reg[c] = W24[(c << 3) + jsub];

  // tail indices/constants
  int vl = tid >> 3, bq = tid & 7;
  int wv = vl >> 1, qq = vl & 1;
  int vo = (bx << 3) + vl;
  float cb1 = 0.f, cb2 = 0.f, cbt = 0.f;
  if (tid < 64) { cb1 = bf1[vo]; cb2 = bf2[vo]; cbt = bta[vo] + btb[vo]; }

  float* mbHc = mbH + (size_t)bx * (NB * NU);    // own h mailbox
  float* mbBc = mbB + (size_t)bx * (NB * NBB);   // own bb mailbox
  int c2 = tid >> 1, hf = tid & 1;               // pusher mapping: 2 thr/consumer

  // ---- init: push h(0) (from hx) to all consumers, tag 0 ----
  if (tid < 64) hstage[bq * 8 + vl] = hx[bq * NU + vo];
  __syncthreads();
  {
    float* dst = mbH + (size_t)c2 * (NB * NU) + (bx << 3);
    #pragma unroll
    for (int i = 0; i < 4; ++i) {
      int b = hf * 4 + i;
      const float* s = &hstage[b * 8];
      float* d = dst + b * NU;
      ast2_tag(d + 0, s[0], s[1], 0u);
      ast2_tag(d + 2, s[2], s[3], 0u);
      ast2_tag(d + 4, s[4], s[5], 0u);
      ast2_tag(d + 6, s[6], s[7], 0u);
    }
  }

  float prv[8];
  if (lane == 0) {
    #pragma unroll
    for (int b = 0; b < 8; ++b) prv[b] = pre[((long)b * NS) * NBB + j1];
  }

  unsigned tagc = 0;                        // t % 255
  for (int t = 0; t < NS; ++t) {
    unsigned tagn = (tagc == 254u) ? 0u : tagc + 1u;

    // ---- poll own h mailbox (32KB, tag==tagc) -> LDS [b][1024] ----
    {
      uint2 rv[16];
      for (;;) {
        unsigned bad = 0;
        #pragma unroll
        for (int i = 0; i < 8; ++i) {
          int f4 = (i << 8) + tid;               // float4 index 0..2047
          rv[2*i]   = ald2u(&mbHc[f4 * 4]);
          rv[2*i+1] = ald2u(&mbHc[f4 * 4 + 2]);
        }
        #pragma unroll
        for (int j = 0; j < 16; ++j)
          bad |= ((rv[j].x ^ tagc) | (rv[j].y ^ tagc)) & 0xFFu;
        if (!bad) break;
        __builtin_amdgcn_s_sleep(1);
      }
      #pragma unroll
      for (int i = 0; i < 8; ++i) {
        int f4 = (i << 8) + tid;
        lsu2[f4 * 2]     = rv[2*i];
        lsu2[f4 * 2 + 1] = rv[2*i+1];
      }
    }
    __syncthreads();

    // ---- stage 1: bb = lecun_tanh(pre + h @ W_hh) ----
    float a1[8];
    #pragma unroll
    for (int b = 0; b < 8; ++b) a1[b] = 0.f;
    #pragma unroll
    for (int c = 0; c < 4; ++c) {
      int idx = (c << 6) + lane;
      float4 w = wreg[c];
      #pragma unroll
      for (int b = 0; b < 8; ++b) {
        float4 hv = ls4[(b << 8) + idx];
        a1[b] += w.x * hv.x + w.y * hv.y + w.z * hv.z + w.w * hv.w;
      }
    }
    #pragma unroll
    for (int m = 1; m < 64; m <<= 1)
      #pragma unroll
      for (int b = 0; b < 8; ++b) a1[b] += __shfl_xor(a1[b], m);
    if (lane == 0) {
      #pragma unroll
      for (int b = 0; b < 8; ++b)
        bbstage[b * 4 + wave] = 1.7159f * tanhf(0.666f * (a1[b] + prv[b]));
    }
    __syncthreads();

    // ---- push bb(t) to all consumers ----
    {
      float* dst = mbB + (size_t)c2 * (NB * NBB) + (bx << 2);
      #pragma unroll
      for (int i = 0; i < 4; ++i) {
        int b = hf * 4 + i;
        const float* s = &bbstage[b * 4];
        float* d = dst + b * NBB;
        ast2_tag(d + 0, s[0], s[1], tagc);
        ast2_tag(d + 2, s[2], s[3], tagc);
      }
    }

    // ---- poll own bb mailbox (16KB, tag==tagc) -> LDS [b][512] ----
    {
      uint2 rv[8];
      for (;;) {
        unsigned bad = 0;
        #pragma unroll
        for (int i = 0; i < 4; ++i) {
          int f4 = (i << 8) + tid;               // float4 index 0..1023
          rv[2*i]   = ald2u(&mbBc[f4 * 4]);
          rv[2*i+1] = ald2u(&mbBc[f4 * 4 + 2]);
        }
        #pragma unroll
        for (int j = 0; j < 8; ++j)
          bad |= ((rv[j].x ^ tagc) | (rv[j].y ^ tagc)) & 0xFFu;
        if (!bad) break;
        __builtin_amdgcn_s_sleep(1);
      }
      #pragma unroll
      for (int i = 0; i < 4; ++i) {
        int f4 = (i << 8) + tid;
        lsu2[f4 * 2]     = rv[2*i];
        lsu2[f4 * 2 + 1] = rv[2*i+1];
      }
    }
    __syncthreads();

    // ---- stage 2: heads + h update ----
    float a2[8];
    #pragma unroll
    for (int b = 0; b < 8; ++b) a2[b] = 0.f;
    #pragma unroll
    for (int c = 0; c < 16; ++c) {
      int idx = (c << 3) + jsub;
      float4 w = w2reg[c];
      #pragma unroll
      for (int b = 0; b < 8; ++b) {
        float4 bv = ls4[(b << 7) + idx];
        a2[b] += w.x * bv.x + w.y * bv.y + w.z * bv.z + w.w * bv.w;
      }
    }
    #pragma unroll
    for (int m = 1; m < 8; m <<= 1)
      #pragma unroll
      for (int b = 0; b < 8; ++b) a2[b] += __shfl_xor(a2[b], m);
    if (jsub == 0) {
      #pragma unroll
      for (int b = 0; b < 8; ++b) lpart[wave][head][v2][b] = a2[b];
    }
    __syncthreads();
    if (tid < 64) {
      float d1 = lpart[wv][0][qq][bq] + cb1;
      float d2 = lpart[wv][1][qq][bq] + cb2;
      float dt = lpart[wv][2][qq][bq] + lpart[wv][3][qq][bq] + cbt;
      float f1 = 1.7159f * tanhf(0.666f * d1);
      float f2 = 1.7159f * tanhf(0.666f * d2);
      float ti = 1.f / (1.f + expf(-dt));
      float hn = f1 * (1.f - ti) + ti * f2;
      hstage[bq * 8 + vl] = hn;
      if (vo < NE) cfc[((long)bq * NS + t) * NE + vo] = hn;   // clean value
      if (t == NS - 1) ast(&hbuf[bq * NU + vo], hn);          // final state out
    }
    if (lane == 0 && t + 1 < NS) {
      #pragma unroll
      for (int b = 0; b < 8; ++b) prv[b] = pre[((long)b * NS + t + 1) * NBB + j1];
    }
    __syncthreads();

    // ---- push h(t+1) to all consumers ----
    if (t + 1 < NS) {
      float* dst = mbH + (size_t)c2 * (NB * NU) + (bx << 3);
      #pragma unroll
      for (int i = 0; i < 4; ++i) {
        int b = hf * 4 + i;
        const float* s = &hstage[b * 8];
        float* d = dst + b * NU;
        ast2_tag(d + 0, s[0], s[1], tagn);
        ast2_tag(d + 2, s[2], s[3], tagn);
        ast2_tag(d + 4, s[4], s[5], tagn);
        ast2_tag(d + 6, s[6], s[7], tagn);
      }
    }
    tagc = tagn;
  }
}

// ---------------- LIF gate + residual (writes x1 into d_out), copy hx ----------------
__global__ __launch_bounds__(256) void lif_kernel(
    const float* __restrict__ x, const float* __restrict__ cfc,
    const float* __restrict__ thr, const float* __restrict__ leak,
    const float* __restrict__ steep, const float* __restrict__ hbuf,
    float* __restrict__ x1, float* __restrict__ outTail)
{
  long i4 = (long)blockIdx.x * blockDim.x + threadIdx.x;  // float4 index
  float4 xv = ((const float4*)x)[i4];
  float4 cv = ((const float4*)cfc)[i4];
  int col = (int)((i4 << 2) % NE);
  float4 tv = *(const float4*)(thr + col);
  float4 lv = *(const float4*)(leak + col);
  float4 sv = *(const float4*)(steep + col);
  float4 r;
#define LIF1(comp) { \
    float th = fabsf(tv.comp) * 0.1f; \
    float ls = 1.f / (1.f + expf(-lv.comp)); \
    float sp = (sv.comp > 20.f) ? sv.comp : log1pf(expf(sv.comp)); \
    float fire = 1.f / (1.f + expf(-sp * (fabsf(cv.comp) - th))); \
    float gate = fire + ls * (1.f - fire); \
    r.comp = xv.comp + cv.comp * gate; }
  LIF1(x) LIF1(y) LIF1(z) LIF1(w)
#undef LIF1
  ((float4*)x1)[i4] = r;
  if (i4 < (NB * NU / 4)) {
    // hbuf was written with sc stores; read it back with sc loads
    const float* hp = hbuf + (i4 << 2);
    float4 hv; hv.x = ald(hp); hv.y = ald(hp + 1); hv.z = ald(hp + 2); hv.w = ald(hp + 3);
    ((float4*)outTail)[i4] = hv;
  }
}

// ---------------- launch ----------------
extern "C" void kernel_launch(void* const* d_in, const int* in_sizes, int n_in,
                              void* d_out, int out_size, void* d_ws, size_t ws_size,
                              hipStream_t stream) {
  (void)in_sizes; (void)n_in; (void)out_size; (void)ws_size;
  const float* x     = (const float*)d_in[0];
  const float* hx    = (const float*)d_in[1];
  const float* ln1g  = (const float*)d_in[2];
  const float* ln1b  = (const float*)d_in[3];
  const float* ln2g  = (const float*)d_in[4];
  const float* ln2b  = (const float*)d_in[5];
  const float* Wbb   = (const float*)d_in[6];
  const float* bbb   = (const float*)d_in[7];
  const float* Wff1  = (const float*)d_in[8];
  const float* bff1  = (const float*)d_in[9];
  const float* Wff2  = (const float*)d_in[10];
  const float* bff2  = (const float*)d_in[11];
  const float* Wta   = (const float*)d_in[12];
  const float* btaP  = (const float*)d_in[13];
  const float* Wtb   = (const float*)d_in[14];
  const float* btbP  = (const float*)d_in[15];
  const float* lthr  = (const float*)d_in[16];
  const float* lleak = (const float*)d_in[17];
  const float* lstp  = (const float*)d_in[18];
  const float* W1    = (const float*)d_in[19];
  const float* b1    = (const float*)d_in[20];
  const float* W2    = (const float*)d_in[21];
  const float* b2    = (const float*)d_in[22];

  char* base = (char*)d_ws;
  // mailboxes live in the normedH region (dead once the pre-GEMMs finish)
  float* mbH = (float*)base;                                         // 4194304 B
  float* mbB = (float*)(base + 4194304);                             // 2097152 B
  unsigned short* normedH = (unsigned short*)base;                   // [0, 25165824)
  float* pre   = (float*)(base + 25165824);                          // [25165824, 58720256)
  float* cfc   = (float*)(base + 58720256);                          // [58720256, 109051904)
  unsigned short* gelu = (unsigned short*)base;                      // [0, 100663296) after cfc consumed
  unsigned short* normedL = (unsigned short*)(base + 109051904);     // [109051904, 134217728)
  unsigned short* h2      = (unsigned short*)(base + 109051904);     // same slot, later phase
  unsigned short* wtbbH = (unsigned short*)(base + 134217728);       // 786432
  float* whhT  = (float*)(base + 135004160);                         // 2097152
  float* whT   = (float*)(base + 137101312);                         // 8388608
  unsigned short* w1t = (unsigned short*)(base + 145489920);         // 4718592
  unsigned short* w2t = (unsigned short*)(base + 150208512);         // 4718592
  float* hbuf  = (float*)(base + 154927104);                         // 32768
  unsigned short* wtbbL = (unsigned short*)(base + 154980352);       // 786432 -> end 155766784
  float* xout  = (float*)d_out;
  float* outTail = xout + (size_t)NBS * NE;
  unsigned short* lnlo_dummy = (unsigned short*)base;                // scratch, overwritten by gelu

  dim3 b328(32, 8);
  // weight prep (transposed, K-contiguous layouts)
  tr_f32_bf16split<<<dim3(512/32, 768/32), b328, 0, stream>>>(Wbb, wtbbH, wtbbL, 768, 512);
  tr_f32<<<dim3(512/32, 1024/32), b328, 0, stream>>>(Wbb + 768*512, whhT, 1024, 512);
  tr_f32<<<dim3(1024/32, 512/32), b328, 0, stream>>>(Wff1, whT + 0*(size_t)NU*NBB, 512, 1024);
  tr_f32<<<dim3(1024/32, 512/32), b328, 0, stream>>>(Wff2, whT + 1*(size_t)NU*NBB, 512, 1024);
  tr_f32<<<dim3(1024/32, 512/32), b328, 0, stream>>>(Wta,  whT + 2*(size_t)NU*NBB, 512, 1024);
  tr_f32<<<dim3(1024/32, 512/32), b328, 0, stream>>>(Wtb,  whT + 3*(size_t)NU*NBB, 512, 1024);
  tr_f32_bf16<<<dim3(3072/32, 768/32), b328, 0, stream>>>(W1, w1t, 768, 3072);
  tr_f32_bf16<<<dim3(768/32, 3072/32), b328, 0, stream>>>(W2, w2t, 3072, 768);

  // LN1 (hi/lo split) + input-projection precompute in ~fp32 precision:
  // pre = nH@wH + nH@wL + nL@wH + b_bb
  ln_kernel<<<NBS/4, 256, 0, stream>>>(x, ln1g, ln1b, normedH, normedL);
  gemm_bf16<0><<<(NBS/128)*(NBB/128), 256, 0, stream>>>(normedH, wtbbH, bbb, nullptr,
                                                        pre, nullptr, NBS, NBB, NE);
  gemm_bf16<3><<<(NBS/128)*(NBB/128), 256, 0, stream>>>(normedH, wtbbL, bbb, nullptr,
                                                        pre, nullptr, NBS, NBB, NE);
  gemm_bf16<3><<<(NBS/128)*(NBB/128), 256, 0, stream>>>(normedL, wtbbH, bbb, nullptr,
                                                        pre, nullptr, NBS, NBB, NE);

  // reset mailboxes to 0xAA (tag 170) so stale generations never alias fresh
  // tags on first touch — per-launch, graph-capture safe, stream-ordered
  // after the pre-GEMMs that read normedH (which this region aliases)
  hipMemsetAsync(base, 0xAA, 6291456, stream);

  scan_kernel<<<NWG, 256, 0, stream>>>(pre, whhT, whT, bff1, bff2, btaP, btbP, hx,
                                       mbH, mbB, cfc, hbuf);

  // LIF gate + residual -> x1 (stored in d_out), plus new_hx copy to output tail
  lif_kernel<<<(NBS*NE/4)/256, 256, 0, stream>>>(x, cfc, lthr, lleak, lstp, hbuf, xout, outTail);
  // LN2 + MLP with fused GELU and residual
  ln_kernel<<<NBS/4, 256, 0, stream>>>(xout, ln2g, ln2b, h2, lnlo_dummy);
  gemm_bf16<1><<<(NBS/128)*(NH/128), 256, 0, stream>>>(h2, w1t, b1, nullptr,
                                                       nullptr, gelu, NBS, NH, NE);
  gemm_bf16<2><<<(NBS/128)*(NE/128), 256, 0, stream>>>(gelu, w2t, b2, xout,
                                                       xout, nullptr, NBS, NE, NH);
}

// Round 9
// 22585.133 us; speedup vs baseline: 2.7770x; 2.7770x over previous
//
#include <hip/hip_runtime.h>
#include <math.h>

#define NB 8
#define NS 2048
#define NE 768
#define NU 1024
#define NBB 512
#define NH 3072
#define NBS (NB*NS)   // 16384
#define NWG 128

typedef float f32x4v __attribute__((ext_vector_type(4)));
typedef __bf16 bf16x8v __attribute__((ext_vector_type(8)));
typedef unsigned short u16x8v __attribute__((ext_vector_type(8)));
typedef unsigned short u16x4v __attribute__((ext_vector_type(4)));

__device__ __forceinline__ unsigned short f2bf(float f) {
  unsigned int u = __builtin_bit_cast(unsigned int, f);
  u = (u + 0x7fffu + ((u >> 16) & 1u)) >> 16;
  return (unsigned short)u;
}
__device__ __forceinline__ float bf2f(unsigned short h) {
  unsigned int u = ((unsigned int)h) << 16;
  return __builtin_bit_cast(float, u);
}

// agent-scope (device) relaxed ops: sc0 sc1 loads/stores, coherent at LLC.
__device__ __forceinline__ float ald(const float* p) {
  return __hip_atomic_load((const float*)p, __ATOMIC_RELAXED, __HIP_MEMORY_SCOPE_AGENT);
}
__device__ __forceinline__ void ast(float* p, float v) {
  __hip_atomic_store(p, v, __ATOMIC_RELAXED, __HIP_MEMORY_SCOPE_AGENT);
}
__device__ __forceinline__ float2 ald2(const float* p) {
  unsigned long long v = __hip_atomic_load((const unsigned long long*)p,
                             __ATOMIC_RELAXED, __HIP_MEMORY_SCOPE_AGENT);
  return __builtin_bit_cast(float2, v);
}
__device__ __forceinline__ unsigned aldu(const unsigned* p) {
  return __hip_atomic_load(p, __ATOMIC_RELAXED, __HIP_MEMORY_SCOPE_AGENT);
}
__device__ __forceinline__ void astu(unsigned* p, unsigned v) {
  __hip_atomic_store(p, v, __ATOMIC_RELAXED, __HIP_MEMORY_SCOPE_AGENT);
}

// ---------------- leader barrier with PRIVATE release lines ----------------
// slots:   bar[bx*16]        (64B apart, written by each block's tid0)
// release: bar[2048 + bx*16] (64B apart, PRIVATE per block -> zero poll sharing)
// Leader (block 0) gathers the 128 slots (2/lane + shfl-min), then broadcasts
// the release tick to all 128 private lines (2 stores/lane). All spins hot.
__device__ __forceinline__ void gbar5(unsigned* bar, int bx, unsigned tick) {
  __syncthreads();                          // drains this block's data stores
  int tid = threadIdx.x;
  if (bx == 0) {
    if (tid < 64) {
      if (tid == 0) astu(&bar[0], tick);    // leader's own arrival
      unsigned m;
      do {
        unsigned a = aldu(&bar[tid * 16]);
        unsigned b = aldu(&bar[(tid + 64) * 16]);
        m = a < b ? a : b;
        #pragma unroll
        for (int s = 1; s < 64; s <<= 1) {
          unsigned o = __shfl_xor(m, s);
          m = m < o ? m : o;
        }
      } while (m < tick);
      astu(&bar[2048 + tid * 16], tick);          // release broadcast
      astu(&bar[2048 + (tid + 64) * 16], tick);
    }
  } else {
    if (tid == 0) {
      astu(&bar[bx * 16], tick);            // arrival
      while (aldu(&bar[2048 + bx * 16]) < tick) {}  // hot spin, private line
    }
  }
  __syncthreads();
}

// ---------------- transpose kernels (weight prep) ----------------
__global__ __launch_bounds__(256) void tr_f32(const float* __restrict__ in,
                                              float* __restrict__ out, int R, int C) {
  __shared__ float tile[32][33];
  int c0 = blockIdx.x * 32, r0 = blockIdx.y * 32;
  int tx = threadIdx.x, ty = threadIdx.y;  // block (32,8)
  #pragma unroll
  for (int i = 0; i < 32; i += 8)
    tile[ty + i][tx] = in[(long)(r0 + ty + i) * C + c0 + tx];
  __syncthreads();
  #pragma unroll
  for (int i = 0; i < 32; i += 8)
    out[(long)(c0 + ty + i) * R + r0 + tx] = tile[tx][ty + i];
}

__global__ __launch_bounds__(256) void tr_f32_bf16(const float* __restrict__ in,
                                                   unsigned short* __restrict__ out, int R, int C) {
  __shared__ float tile[32][33];
  int c0 = blockIdx.x * 32, r0 = blockIdx.y * 32;
  int tx = threadIdx.x, ty = threadIdx.y;
  #pragma unroll
  for (int i = 0; i < 32; i += 8)
    tile[ty + i][tx] = in[(long)(r0 + ty + i) * C + c0 + tx];
  __syncthreads();
  #pragma unroll
  for (int i = 0; i < 32; i += 8)
    out[(long)(c0 + ty + i) * R + r0 + tx] = f2bf(tile[tx][ty + i]);
}

// transpose + split into bf16 hi/lo pair (for ~fp32-precision GEMM)
__global__ __launch_bounds__(256) void tr_f32_bf16split(const float* __restrict__ in,
    unsigned short* __restrict__ oh, unsigned short* __restrict__ ol, int R, int C) {
  __shared__ float tile[32][33];
  int c0 = blockIdx.x * 32, r0 = blockIdx.y * 32;
  int tx = threadIdx.x, ty = threadIdx.y;
  #pragma unroll
  for (int i = 0; i < 32; i += 8)
    tile[ty + i][tx] = in[(long)(r0 + ty + i) * C + c0 + tx];
  __syncthreads();
  #pragma unroll
  for (int i = 0; i < 32; i += 8) {
    float v = tile[tx][ty + i];
    unsigned short h = f2bf(v);
    long idx = (long)(c0 + ty + i) * R + r0 + tx;
    oh[idx] = h;
    ol[idx] = f2bf(v - bf2f(h));
  }
}

// ---------------- LayerNorm (one wave per row of 768) -> bf16 hi/lo out ----------------
__global__ __launch_bounds__(256) void ln_kernel(const float* __restrict__ in,
    const float* __restrict__ gw, const float* __restrict__ bw,
    unsigned short* __restrict__ outh, unsigned short* __restrict__ outl) {
  int lane = threadIdx.x & 63;
  long row = (long)blockIdx.x * 4 + (threadIdx.x >> 6);
  const float4* rp = (const float4*)(in + row * NE);
  float4 v[3];
  float s = 0.f, sq = 0.f;
  #pragma unroll
  for (int j = 0; j < 3; ++j) {
    v[j] = rp[lane + j * 64];
    s += v[j].x + v[j].y + v[j].z + v[j].w;
    sq += v[j].x*v[j].x + v[j].y*v[j].y + v[j].z*v[j].z + v[j].w*v[j].w;
  }
  #pragma unroll
  for (int m = 1; m < 64; m <<= 1) { s += __shfl_xor(s, m); sq += __shfl_xor(sq, m); }
  float mu = s * (1.f / NE);
  float rs = rsqrtf(sq * (1.f / NE) - mu * mu + 1e-5f);
  #pragma unroll
  for (int j = 0; j < 3; ++j) {
    int c4 = lane + j * 64;
    float4 g4 = ((const float4*)gw)[c4];
    float4 b4 = ((const float4*)bw)[c4];
    float f0 = (v[j].x - mu) * rs * g4.x + b4.x;
    float f1 = (v[j].y - mu) * rs * g4.y + b4.y;
    float f2 = (v[j].z - mu) * rs * g4.z + b4.z;
    float f3 = (v[j].w - mu) * rs * g4.w + b4.w;
    u16x4v oh, ol;
    oh[0] = f2bf(f0); ol[0] = f2bf(f0 - bf2f(oh[0]));
    oh[1] = f2bf(f1); ol[1] = f2bf(f1 - bf2f(oh[1]));
    oh[2] = f2bf(f2); ol[2] = f2bf(f2 - bf2f(oh[2]));
    oh[3] = f2bf(f3); ol[3] = f2bf(f3 - bf2f(oh[3]));
    *(u16x4v*)(outh + row * NE + (long)c4 * 4) = oh;
    *(u16x4v*)(outl + row * NE + (long)c4 * 4) = ol;
  }
}

// ---------------- bf16 MFMA GEMM: C[M,N] = A[M,K] @ Bt[N,K]^T (+bias, epilogue) ---
// EPI 0: Cf = acc + bias            (fp32 out)
// EPI 1: Cb = bf16(gelu(acc+bias))  (bf16 out)
// EPI 2: Cf = acc + bias + res      (fp32 out, residual add; res may alias Cf)
// EPI 3: Cf += acc                  (fp32 accumulate, no bias)
template<int EPI>
__global__ __launch_bounds__(256) void gemm_bf16(
    const unsigned short* __restrict__ A, const unsigned short* __restrict__ Bt,
    const float* __restrict__ bias, const float* res,
    float* Cf, unsigned short* Cb, int M, int N, int K)
{
  __shared__ unsigned short lA[128][72];
  __shared__ unsigned short lB[128][72];
  int tid = threadIdx.x;
  int lane = tid & 63, wave = tid >> 6;
  int wr = wave >> 1, wc = wave & 1;
  int r15 = lane & 15, hi = lane >> 4;
  int ntn = N >> 7;
  long m0 = (long)(blockIdx.x / ntn) << 7;
  long n0 = (long)(blockIdx.x % ntn) << 7;
  f32x4v acc[4][4];
  #pragma unroll
  for (int m = 0; m < 4; ++m)
    #pragma unroll
    for (int n = 0; n < 4; ++n) acc[m][n] = (f32x4v){0.f, 0.f, 0.f, 0.f};

  for (int kt = 0; kt < K; kt += 64) {
    u16x8v ra[4], rb[4];
    #pragma unroll
    for (int i = 0; i < 4; ++i) {
      int c = tid + (i << 8);
      int rw = c >> 3, ko = (c & 7) << 3;
      ra[i] = *(const u16x8v*)(A + (m0 + rw) * K + kt + ko);
      rb[i] = *(const u16x8v*)(Bt + (n0 + rw) * K + kt + ko);
    }
    __syncthreads();
    #pragma unroll
    for (int i = 0; i < 4; ++i) {
      int c = tid + (i << 8);
      int rw = c >> 3, ko = (c & 7) << 3;
      *(u16x8v*)(&lA[rw][ko]) = ra[i];
      *(u16x8v*)(&lB[rw][ko]) = rb[i];
    }
    __syncthreads();
    #pragma unroll
    for (int ks = 0; ks < 64; ks += 32) {
      bf16x8v af[4], bfr[4];
      #pragma unroll
      for (int m = 0; m < 4; ++m)
        af[m] = *(const bf16x8v*)(&lA[wr * 64 + m * 16 + r15][ks + hi * 8]);
      #pragma unroll
      for (int n = 0; n < 4; ++n)
        bfr[n] = *(const bf16x8v*)(&lB[wc * 64 + n * 16 + r15][ks + hi * 8]);
      #pragma unroll
      for (int m = 0; m < 4; ++m)
        #pragma unroll
        for (int n = 0; n < 4; ++n)
          acc[m][n] = __builtin_amdgcn_mfma_f32_16x16x32_bf16(af[m], bfr[n], acc[m][n], 0, 0, 0);
    }
  }
  #pragma unroll
  for (int m = 0; m < 4; ++m) {
    long rbase = m0 + wr * 64 + m * 16 + hi * 4;
    #pragma unroll
    for (int n = 0; n < 4; ++n) {
      long cg = n0 + wc * 64 + n * 16 + r15;
      float bs = (EPI == 3) ? 0.f : bias[cg];
      #pragma unroll
      for (int e = 0; e < 4; ++e) {
        long row = rbase + e;
        float vv = acc[m][n][e] + bs;
        if (EPI == 0) {
          Cf[row * N + cg] = vv;
        } else if (EPI == 1) {
          float gl = 0.5f * vv * (1.f + erff(vv * 0.70710678118f));
          Cb[row * N + cg] = f2bf(gl);
        } else if (EPI == 2) {
          Cf[row * N + cg] = vv + res[row * N + cg];
        } else {
          Cf[row * N + cg] += vv;
        }
      }
    }
  }
}

// ---------------- persistent scan kernel ----------------
// 128 WGs x 256 thr; 2 gbar5 barriers per timestep.
// Critical-path hygiene: pre lives in an LDS block-cache (reloaded every 64
// steps, coalesced); the cfc HBM store is issued AFTER the h-ready barrier so
// its drain overlaps the next step's staging; weights register-hoisted.
__global__ __launch_bounds__(256) void scan_kernel(
    const float* __restrict__ pre, const float* __restrict__ WhhT,
    const float* __restrict__ WhT,
    const float* __restrict__ bf1, const float* __restrict__ bf2,
    const float* __restrict__ bta, const float* __restrict__ btb,
    const float* __restrict__ hx,
    float* hbuf, float* bbf, float* __restrict__ cfc, unsigned* bar)
{
  __shared__ float lsd[NB * NU];            // h staging (32KB); bb reuses first 16KB
  __shared__ float4 lpre[512];              // pre cache: [b][t&63] -> 4 j's (8KB)
  __shared__ float lpart[4][4][2][8];
  int tid = threadIdx.x;
  int lane = tid & 63, wave = tid >> 6;
  int bx = blockIdx.x;
  int j1 = (bx << 2) + wave;
  int head = lane >> 4, v2 = (lane >> 3) & 1, jsub = lane & 7;
  int vg = (bx << 3) + (wave << 1) + v2;
  const float4* W14 = (const float4*)(WhhT + (long)j1 * NU);
  const float4* W24 = (const float4*)(WhT + ((long)head * NU + vg) * NBB);
  const float4* ls4 = (const float4*)lsd;
  float2* ls2 = (float2*)lsd;
  const float* lpf = (const float*)lpre;
  unsigned tick = 0;

  // hoist this wave's Whh row (4KB across 64 lanes -> 4 float4/lane)
  float4 wreg[4];
  #pragma unroll
  for (int c = 0; c < 4; ++c) wreg[c] = W14[(c << 6) + lane];
  // hoist stage-2 weight rows (16 float4/lane = 64 VGPR)
  float4 w2reg[16];
  #pragma unroll
  for (int c = 0; c < 16; ++c) w2reg[c] = W24[(c << 3) + jsub];

  // tail-update constants
  int vl = tid >> 3, bq = tid & 7;
  int wv = vl >> 1, qq = vl & 1;
  int vo = (bx << 3) + vl;
  float cb1 = 0.f, cb2 = 0.f, cbt = 0.f;
  if (tid < 64) { cb1 = bf1[vo]; cb2 = bf2[vo]; cbt = bta[vo] + btb[vo]; }

  // init h state (sc-stores so later sc-loads observe it)
  if (tid < 64) ast(&hbuf[(bx << 6) + tid], hx[(bx << 6) + tid]);
  gbar5(bar, bx, ++tick);

  for (int t = 0; t < NS; ++t) {
    // ---- bulk pre reload every 64 steps (coalesced float4; co-drains with
    //      the h staging at the next __syncthreads) ----
    if ((t & 63) == 0) {
      #pragma unroll
      for (int i = 0; i < 2; ++i) {
        int idx = (i << 8) + tid;              // 0..511
        int b = idx >> 6, tq = idx & 63;
        lpre[idx] = *(const float4*)(pre + ((long)b * NS + t + tq) * NBB + (bx << 2));
      }
    }
    // ---- stage h into LDS (batched 8B sc-loads) ----
    {
      float2 rv[16];
      #pragma unroll
      for (int i = 0; i < 16; ++i) rv[i] = ald2(&hbuf[(((i << 8) + tid) << 1)]);
      #pragma unroll
      for (int i = 0; i < 16; ++i) ls2[(i << 8) + tid] = rv[i];
    }
    __syncthreads();

    // ---- stage 1: bb = lecun_tanh(pre + h @ W_hh) ----
    float a1[8];
    #pragma unroll
    for (int b = 0; b < 8; ++b) a1[b] = 0.f;
    #pragma unroll
    for (int c = 0; c < 4; ++c) {
      int idx = (c << 6) + lane;
      float4 w = wreg[c];
      #pragma unroll
      for (int b = 0; b < 8; ++b) {
        float4 hv = ls4[(b << 8) + idx];
        a1[b] += w.x * hv.x + w.y * hv.y + w.z * hv.z + w.w * hv.w;
      }
    }
    #pragma unroll
    for (int m = 1; m < 64; m <<= 1)
      #pragma unroll
      for (int b = 0; b < 8; ++b) a1[b] += __shfl_xor(a1[b], m);
    if (lane == 0) {
      int tq = t & 63;
      #pragma unroll
      for (int b = 0; b < 8; ++b) {
        float s = a1[b] + lpf[(((b << 6) | tq) << 2) + wave];
        ast(&bbf[b * NBB + j1], 1.7159f * tanhf(0.666f * s));
      }
    }
    gbar5(bar, bx, ++tick);

    // ---- stage bb into LDS ----
    {
      float2 rv[8];
      #pragma unroll
      for (int i = 0; i < 8; ++i) rv[i] = ald2(&bbf[(((i << 8) + tid) << 1)]);
      #pragma unroll
      for (int i = 0; i < 8; ++i) ls2[(i << 8) + tid] = rv[i];
    }
    __syncthreads();

    // ---- stage 2: heads + h update ----
    float a2[8];
    #pragma unroll
    for (int b = 0; b < 8; ++b) a2[b] = 0.f;
    #pragma unroll
    for (int c = 0; c < 16; ++c) {
      int idx = (c << 3) + jsub;
      float4 w = w2reg[c];
      #pragma unroll
      for (int b = 0; b < 8; ++b) {
        float4 bv = ls4[(b << 7) + idx];
        a2[b] += w.x * bv.x + w.y * bv.y + w.z * bv.z + w.w * bv.w;
      }
    }
    #pragma unroll
    for (int m = 1; m < 8; m <<= 1)
      #pragma unroll
      for (int b = 0; b < 8; ++b) a2[b] += __shfl_xor(a2[b], m);
    if (jsub == 0) {
      #pragma unroll
      for (int b = 0; b < 8; ++b) lpart[wave][head][v2][b] = a2[b];
    }
    __syncthreads();
    float hn = 0.f;
    if (tid < 64) {
      float d1 = lpart[wv][0][qq][bq] + cb1;
      float d2 = lpart[wv][1][qq][bq] + cb2;
      float dt = lpart[wv][2][qq][bq] + lpart[wv][3][qq][bq] + cbt;
      float f1 = 1.7159f * tanhf(0.666f * d1);
      float f2 = 1.7159f * tanhf(0.666f * d2);
      float ti = 1.f / (1.f + expf(-dt));
      hn = f1 * (1.f - ti) + ti * f2;
      ast(&hbuf[bq * NU + vo], hn);
    }
    gbar5(bar, bx, ++tick);
    // cfc store AFTER the barrier: HBM write drain overlaps next step
    if (tid < 64 && vo < NE) cfc[((long)bq * NS + t) * NE + vo] = hn;
  }
}

// ---------------- LIF gate + residual (writes x1 into d_out), copy hx ----------------
__global__ __launch_bounds__(256) void lif_kernel(
    const float* __restrict__ x, const float* __restrict__ cfc,
    const float* __restrict__ thr, const float* __restrict__ leak,
    const float* __restrict__ steep, const float* __restrict__ hbuf,
    float* __restrict__ x1, float* __restrict__ outTail)
{
  long i4 = (long)blockIdx.x * blockDim.x + threadIdx.x;  // float4 index
  float4 xv = ((const float4*)x)[i4];
  float4 cv = ((const float4*)cfc)[i4];
  int col = (int)((i4 << 2) % NE);
  float4 tv = *(const float4*)(thr + col);
  float4 lv = *(const float4*)(leak + col);
  float4 sv = *(const float4*)(steep + col);
  float4 r;
#define LIF1(comp) { \
    float th = fabsf(tv.comp) * 0.1f; \
    float ls = 1.f / (1.f + expf(-lv.comp)); \
    float sp = (sv.comp > 20.f) ? sv.comp : log1pf(expf(sv.comp)); \
    float fire = 1.f / (1.f + expf(-sp * (fabsf(cv.comp) - th))); \
    float gate = fire + ls * (1.f - fire); \
    r.comp = xv.comp + cv.comp * gate; }
  LIF1(x) LIF1(y) LIF1(z) LIF1(w)
#undef LIF1
  ((float4*)x1)[i4] = r;
  if (i4 < (NB * NU / 4)) {
    // hbuf was written with sc stores; read it back with sc loads
    const float* hp = hbuf + (i4 << 2);
    float4 hv; hv.x = ald(hp); hv.y = ald(hp + 1); hv.z = ald(hp + 2); hv.w = ald(hp + 3);
    ((float4*)outTail)[i4] = hv;
  }
}

// ---------------- launch ----------------
extern "C" void kernel_launch(void* const* d_in, const int* in_sizes, int n_in,
                              void* d_out, int out_size, void* d_ws, size_t ws_size,
                              hipStream_t stream) {
  (void)in_sizes; (void)n_in; (void)out_size; (void)ws_size;
  const float* x     = (const float*)d_in[0];
  const float* hx    = (const float*)d_in[1];
  const float* ln1g  = (const float*)d_in[2];
  const float* ln1b  = (const float*)d_in[3];
  const float* ln2g  = (const float*)d_in[4];
  const float* ln2b  = (const float*)d_in[5];
  const float* Wbb   = (const float*)d_in[6];
  const float* bbb   = (const float*)d_in[7];
  const float* Wff1  = (const float*)d_in[8];
  const float* bff1  = (const float*)d_in[9];
  const float* Wff2  = (const float*)d_in[10];
  const float* bff2  = (const float*)d_in[11];
  const float* Wta   = (const float*)d_in[12];
  const float* btaP  = (const float*)d_in[13];
  const float* Wtb   = (const float*)d_in[14];
  const float* btbP  = (const float*)d_in[15];
  const float* lthr  = (const float*)d_in[16];
  const float* lleak = (const float*)d_in[17];
  const float* lstp  = (const float*)d_in[18];
  const float* W1    = (const float*)d_in[19];
  const float* b1    = (const float*)d_in[20];
  const float* W2    = (const float*)d_in[21];
  const float* b2    = (const float*)d_in[22];

  char* base = (char*)d_ws;
  unsigned short* normedH = (unsigned short*)base;                   // [0, 25165824)
  float* pre   = (float*)(base + 25165824);                          // [25165824, 58720256)
  float* cfc   = (float*)(base + 58720256);                          // [58720256, 109051904)
  unsigned short* gelu = (unsigned short*)base;                      // [0, 100663296) after cfc consumed
  unsigned short* normedL = (unsigned short*)(base + 109051904);     // [109051904, 134217728)
  unsigned short* h2      = (unsigned short*)(base + 109051904);     // same slot, later phase
  // barrier region: 16KB inside the normedL/h2 slot (dead during the scan;
  // h2 is written only after the scan completes)
  unsigned* bar = (unsigned*)(base + 125829120);                     // 16384 B
  unsigned short* wtbbH = (unsigned short*)(base + 134217728);       // 786432
  float* whhT  = (float*)(base + 135004160);                         // 2097152
  float* whT   = (float*)(base + 137101312);                         // 8388608
  unsigned short* w1t = (unsigned short*)(base + 145489920);         // 4718592
  unsigned short* w2t = (unsigned short*)(base + 150208512);         // 4718592
  float* hbuf  = (float*)(base + 154927104);                         // 32768
  float* bbf   = (float*)(base + 154959872);                         // 16384
  unsigned short* wtbbL = (unsigned short*)(base + 154980352);       // 786432 -> end 155766784
  float* xout  = (float*)d_out;
  float* outTail = xout + (size_t)NBS * NE;
  unsigned short* lnlo_dummy = (unsigned short*)base;                // scratch, overwritten by gelu

  dim3 b328(32, 8);
  // weight prep (transposed, K-contiguous layouts)
  tr_f32_bf16split<<<dim3(512/32, 768/32), b328, 0, stream>>>(Wbb, wtbbH, wtbbL, 768, 512);
  tr_f32<<<dim3(512/32, 1024/32), b328, 0, stream>>>(Wbb + 768*512, whhT, 1024, 512);
  tr_f32<<<dim3(1024/32, 512/32), b328, 0, stream>>>(Wff1, whT + 0*(size_t)NU*NBB, 512, 1024);
  tr_f32<<<dim3(1024/32, 512/32), b328, 0, stream>>>(Wff2, whT + 1*(size_t)NU*NBB, 512, 1024);
  tr_f32<<<dim3(1024/32, 512/32), b328, 0, stream>>>(Wta,  whT + 2*(size_t)NU*NBB, 512, 1024);
  tr_f32<<<dim3(1024/32, 512/32), b328, 0, stream>>>(Wtb,  whT + 3*(size_t)NU*NBB, 512, 1024);
  tr_f32_bf16<<<dim3(3072/32, 768/32), b328, 0, stream>>>(W1, w1t, 768, 3072);
  tr_f32_bf16<<<dim3(768/32, 3072/32), b328, 0, stream>>>(W2, w2t, 3072, 768);

  // LN1 (hi/lo split) + input-projection precompute in ~fp32 precision:
  // pre = nH@wH + nH@wL + nL@wH + b_bb
  ln_kernel<<<NBS/4, 256, 0, stream>>>(x, ln1g, ln1b, normedH, normedL);
  gemm_bf16<0><<<(NBS/128)*(NBB/128), 256, 0, stream>>>(normedH, wtbbH, bbb, nullptr,
                                                        pre, nullptr, NBS, NBB, NE);
  gemm_bf16<3><<<(NBS/128)*(NBB/128), 256, 0, stream>>>(normedH, wtbbL, bbb, nullptr,
                                                        pre, nullptr, NBS, NBB, NE);
  gemm_bf16<3><<<(NBS/128)*(NBB/128), 256, 0, stream>>>(normedL, wtbbH, bbb, nullptr,
                                                        pre, nullptr, NBS, NBB, NE);

  // zero the barrier region (stream-ordered after the pre-GEMMs that read
  // normedL, which this region aliases)
  hipMemsetAsync(bar, 0, 16384, stream);

  scan_kernel<<<NWG, 256, 0, stream>>>(pre, whhT, whT, bff1, bff2, btaP, btbP, hx,
                                       hbuf, bbf, cfc, bar);

  // LIF gate + residual -> x1 (stored in d_out), plus new_hx copy to output tail
  lif_kernel<<<(NBS*NE/4)/256, 256, 0, stream>>>(x, cfc, lthr, lleak, lstp, hbuf, xout, outTail);
  // LN2 + MLP with fused GELU and residual
  ln_kernel<<<NBS/4, 256, 0, stream>>>(xout, ln2g, ln2b, h2, lnlo_dummy);
  gemm_bf16<1><<<(NBS/128)*(NH/128), 256, 0, stream>>>(h2, w1t, b1, nullptr,
                                                       nullptr, gelu, NBS, NH, NE);
  gemm_bf16<2><<<(NBS/128)*(NE/128), 256, 0, stream>>>(gelu, w2t, b2, xout,
                                                       xout, nullptr, NBS, NE, NH);
}